// Round 7
// baseline (212.544 us; speedup 1.0000x reference)
//
#include <hip/hip_runtime.h>
#include <hip/hip_bf16.h>
#include <cstdint>
#include <cstddef>

typedef __bf16 bf16x8 __attribute__((ext_vector_type(8)));
typedef __bf16 bf16x4 __attribute__((ext_vector_type(4)));
typedef float f32x4 __attribute__((ext_vector_type(4)));

#define BATCH 16
#define MDIM 1024
#define NDIM 4096
#define KDIM 1024
#define BM 256
#define BN 256
#define BK 64
#define NKT (KDIM / BK)  // 16

__device__ __forceinline__ void gload_lds16(const void* g, void* l) {
  __builtin_amdgcn_global_load_lds(
      (const __attribute__((address_space(1))) void*)g,
      (__attribute__((address_space(3))) void*)l, 16, 0, 0);
}

#define BAR() __builtin_amdgcn_s_barrier()
#define SB() __builtin_amdgcn_sched_barrier(0)
#define FENCE() asm volatile("" ::: "memory")
#define LGKM0()                                        \
  do {                                                 \
    asm volatile("s_waitcnt lgkmcnt(0)" ::: "memory"); \
    SB();                                              \
  } while (0)
#define VMC36()                                        \
  do {                                                 \
    asm volatile("s_waitcnt vmcnt(36)" ::: "memory");  \
    SB();                                              \
  } while (0)

// ---------------------------------------------------------------------------
// Kernel 1: W~[b][o][i] bf16 into workspace (~10us).  (unchanged)
// ---------------------------------------------------------------------------
__global__ __launch_bounds__(256) void modw_kernel(
    const float* __restrict__ weight, const float* __restrict__ y,
    __bf16* __restrict__ wm) {
  const int blk = blockIdx.x;  // 16384
  const int b = blk & 15;
  const int o = blk >> 4;
  const int t = threadIdx.x;
  const float4 w4 = reinterpret_cast<const float4*>(weight + (size_t)o * KDIM)[t];
  const float4 y4 = reinterpret_cast<const float4*>(y + (size_t)b * KDIM)[t];
  const float p0 = w4.x * y4.x, p1 = w4.y * y4.y;
  const float p2 = w4.z * y4.z, p3 = w4.w * y4.w;
  float s = p0 * p0 + p1 * p1 + p2 * p2 + p3 * p3;
#pragma unroll
  for (int off = 32; off >= 1; off >>= 1) s += __shfl_xor(s, off, 64);
  __shared__ float ps[4];
  if ((t & 63) == 0) ps[t >> 6] = s;
  __syncthreads();
  const float tot = ps[0] + ps[1] + ps[2] + ps[3];
  const float scale = 0.03125f;  // 1/sqrt(1024)
  const float dn = scale * rsqrtf(scale * scale * tot + 1e-8f);
  bf16x4 v;
  v[0] = (__bf16)(p0 * dn);
  v[1] = (__bf16)(p1 * dn);
  v[2] = (__bf16)(p2 * dn);
  v[3] = (__bf16)(p3 * dn);
  *reinterpret_cast<bf16x4*>(wm + ((size_t)b * MDIM + o) * KDIM + t * 4) = v;
}

// ---------------------------------------------------------------------------
// Kernel 2: fused 256x256x64, 8 waves, ONE sync point per K-tile, frag
// read-ahead (R6), and NOW a 2-TILE-DEEP A PIPELINE (A triple-buffered,
// 160 KB LDS) so that NO wait in the steady-state loop covers a load
// younger than ~1 full K-tile (~2500+ cyc):
//   - stage A(t+2) issued at tile t, drained at tile (t+1)'s boundary
//     via vmcnt(36)  [queue: stage(t+1) 4 | br(t+2) 32 | stage(t+2) 4]
//   - br(t+1) loads drained by writeB's implicit wait at tile t's R0,
//     issued during tile t-1 (~1 tile old)
// This removes the young drain (stage issued ~2 regions before its wait)
// that R1/R5/R6 all shared -- the m201 mechanism (waits only on >=4-phase-
// old loads) applied to the fused structure.  Numerics bit-identical.
// Tail: wrapped-clamp prefetch keeps per-thread VMEM counts uniform;
// clamped stages land in buffers never read again (3-buffer rotation).
// ---------------------------------------------------------------------------
__global__ __launch_bounds__(512, 2) void gemm_kernel(
    const __bf16* __restrict__ Wm, const float* __restrict__ E,
    float* __restrict__ out) {
  const int orig = blockIdx.x;  // 1024
  const int wg = (orig & 7) * 128 + (orig >> 3);  // bijective XCD swizzle
  const int mt = wg & 3;
  const int nt = (wg >> 2) & 15;
  const int b = wg >> 6;
  const int m0 = mt * BM, n0 = nt * BN;

  __shared__ __align__(16) char smem[163840];
  char* const A0_ = smem;
  char* const A1_ = smem + 32768;
  char* const A2_ = smem + 65536;
  char* const B0_ = smem + 98304;
  char* const B1_ = smem + 131072;

  const int tid = threadIdx.x;  // 512
  const int lane = tid & 63;
  const int wid = tid >> 6;  // 0..7
  const int wr = wid >> 2;   // 0..1
  const int wc = wid & 3;    // 0..3
  const int ml = lane & 15;
  const int kg = lane >> 4;

  // ---- A staging ----
  const int arow = tid >> 3;                      // 0..63, +64/round
  const int aswz = ((tid & 7) ^ (arow & 7)) * 8;  // pre-swizzled k-elem off
  const __bf16* Ag = Wm + ((size_t)(b * MDIM + m0 + arow)) * KDIM + aswz;
  const int aldsOff = tid * 16;

  // ---- B staging ----
  const int bn1 = tid & 63;
  const int bkg = tid >> 6;
  typedef const __attribute__((address_space(1))) float gfloat;
  gfloat* Eg = (gfloat*)(E + (size_t)b * KDIM * NDIM +
                         (size_t)(bkg * 8) * NDIM + n0 + bn1);
  int bwr[4];
#pragma unroll
  for (int c = 0; c < 4; ++c) {
    const int n = bn1 + 64 * c;
    bwr[c] = n * 128 + ((bkg * 16) ^ ((n & 7) << 4));
  }

  // ---- compute-side fragment addressing ----
  const int colA = (kg * 16) ^ ((ml & 7) << 4);
  const int arB = (wr * 128 + ml) * 128;
  const int brB = (wc * 64 + ml) * 128;

  f32x4 acc[8][4];
#pragma unroll
  for (int i = 0; i < 8; ++i)
#pragma unroll
    for (int j = 0; j < 4; ++j) acc[i][j] = (f32x4){0.f, 0.f, 0.f, 0.f};

  auto stageA = [&](char* Ab, int kt) {
#pragma unroll
    for (int r = 0; r < 4; ++r)
      gload_lds16(Ag + (size_t)(64 * r) * KDIM + kt * BK,
                  Ab + aldsOff + r * 8192);
  };
  auto loadB = [&](float (&brr)[4][8], int kt) {
#pragma unroll
    for (int c = 0; c < 4; ++c)
#pragma unroll
      for (int j = 0; j < 8; ++j)
        brr[c][j] = Eg[(size_t)(kt * BK + j) * NDIM + 64 * c];
  };
  auto writeB = [&](char* Bb, float (&brr)[4][8]) {
#pragma unroll
    for (int c = 0; c < 4; ++c) {
      bf16x8 v;
#pragma unroll
      for (int j = 0; j < 8; ++j) v[j] = (__bf16)brr[c][j];
      *reinterpret_cast<bf16x8*>(Bb + bwr[c]) = v;
    }
  };
  auto rdA = [&](bf16x8 (&d)[4], const char* Ab, int qm, int kk) {
#pragma unroll
    for (int i = 0; i < 4; ++i)
      d[i] = *reinterpret_cast<const bf16x8*>(Ab + arB + (qm * 4 + i) * 2048 +
                                              (colA ^ (kk * 64)));
  };
  auto rdB = [&](bf16x8 (&d)[4], const char* Bb, int kk) {
#pragma unroll
    for (int nf = 0; nf < 4; ++nf)
      d[nf] = *reinterpret_cast<const bf16x8*>(Bb + brB + nf * 2048 +
                                               (colA ^ (kk * 64)));
  };
  auto mfma16 = [&](bf16x8 (&a)[4], bf16x8 (&bv)[4], int qm) {
    __builtin_amdgcn_s_setprio(1);
#pragma unroll
    for (int i = 0; i < 4; ++i)
#pragma unroll
      for (int nf = 0; nf < 4; ++nf)
        acc[qm * 4 + i][nf] = __builtin_amdgcn_mfma_f32_16x16x32_bf16(
            a[i], bv[nf], acc[qm * 4 + i][nf], 0, 0, 0);
    __builtin_amdgcn_s_setprio(0);
  };

  float br[4][8];          // B reg-stage, persistent
  bf16x8 af0[4], af1[4];   // rotating frag slots
  bf16x8 bf0[4], bf1[4];

  // ---- prologue: tile0 -> A0/B0 (full drain once); br <- tile1;
  //      stage A1 <- tile1; queue on loop entry = [br(1) 32, stage(1) 4] ----
  {
    float brT[4][8];
    stageA(A0_, 0);  // queue [A0(4)]
    FENCE();
    loadB(brT, 0);     // [A0(4), brT(32)]
    writeB(B0_, brT);  // implicit vmcnt(0): all drained
    loadB(br, 1);      // [br1(32)]
    FENCE();           // pin order: br(1) older than stage(1)
    stageA(A1_, 1);    // [br1(32), stage1(4)]  == steady-state entry
    LGKM0();
    BAR();
    rdA(af0, A0_, 0, 0);  // read-ahead for t=0 R0
    rdB(bf0, B0_, 0);
  }

  char* Acur = A0_;  // read at tile t
  char* Anxt = A1_;  // read at tile t+1 (stage drained at t's boundary)
  char* Astg = A2_;  // stage target for tile t+2
  char* Bc = B0_;
  char* Bo = B1_;

#pragma unroll 1
  for (int t = 0; t < NKT; ++t) {
    const int t2 = (t + 2 < NKT) ? t + 2 : (t + 2 - NKT);  // wrap-clamp

    // R0: read-ahead (q1,k0); publish B(t+1); MFMA q0k0
    rdA(af1, Acur, 1, 0);
    writeB(Bo, br);  // implicit wait: br(t+1), issued during t-1 (~1 tile)
    mfma16(af0, bf0, 0);

    // R0.5/R1: prefetch br(t+2); read-ahead (k1),(q0,k1); stage A(t+2); MFMA q1k0
    loadB(br, t2);
    FENCE();  // pin VMEM order: br(t+2) older than stage(t+2)
    rdB(bf1, Bc, 1);
    rdA(af0, Acur, 0, 1);
    stageA(Astg, t2);
    mfma16(af1, bf0, 1);

    // R2: read-ahead (q1,k1); MFMA q0k1; single sync point
    rdA(af1, Acur, 1, 1);
    mfma16(af0, bf1, 0);
    LGKM0();  // my frag reads + my B ds_writes done
    VMC36();  // queue [stage(t+1) 4 | br(t+2) 32 | stage(t+2) 4] = 40
              // -> drains ONLY stage(t+1), issued during tile t-1
    BAR();

    // R3: read-ahead tile t+1 frags from Anxt/Bo; MFMA q1k1
    rdA(af0, Anxt, 0, 0);
    rdB(bf0, Bo, 0);
    mfma16(af1, bf1, 1);

    // rotate buffers
    char* ta = Acur; Acur = Anxt; Anxt = Astg; Astg = ta;
    char* tb = Bc; Bc = Bo; Bo = tb;
  }

  // ---- epilogue (unchanged) ----
  float* ob = out + ((size_t)(b * MDIM + m0 + wr * 128 + kg * 4)) * NDIM +
              n0 + wc * 64 + ml;
#pragma unroll
  for (int mf = 0; mf < 8; ++mf)
#pragma unroll
    for (int nf = 0; nf < 4; ++nf) {
      const f32x4 a = acc[mf][nf];
      float* p = ob + (size_t)mf * 16 * NDIM + nf * 16;
#pragma unroll
      for (int q = 0; q < 4; ++q) p[(size_t)q * NDIM] = a[q];
    }
}

extern "C" void kernel_launch(void* const* d_in, const int* in_sizes, int n_in,
                              void* d_out, int out_size, void* d_ws,
                              size_t ws_size, hipStream_t stream) {
  (void)in_sizes;
  (void)n_in;
  (void)out_size;
  (void)ws_size;
  const float* Efou = (const float*)d_in[0];
  const float* y = (const float*)d_in[1];
  const float* weight = (const float*)d_in[2];
  float* outp = (float*)d_out;
  __bf16* wm = (__bf16*)d_ws;  // 32 MB

  modw_kernel<<<dim3(BATCH * MDIM), dim3(256), 0, stream>>>(weight, y, wm);
  gemm_kernel<<<dim3(BATCH * (MDIM / BM) * (NDIM / BN)), dim3(512), 0,
                stream>>>(wm, Efou, outp);
}